// Round 11
// baseline (167.619 us; speedup 1.0000x reference)
//
#include <hip/hip_runtime.h>

// NearestEmbed via MFMA (Round 8).
// R7: occupancy 2x'd but dur ~flat -> VALU (40%) is the busiest pipe; tracking
// dominated it. This round: (1) stage -2w, init acc C with w2+128 so the MFMA
// chain EMITS the score (drop 8 fma/t); (2) keyed top-3 tracking: score+128>0
// always, key=(bits&~511)|k, 5-op min/max insert (drop 8x8-op cmp/sel);
// (3) trunc splits; (4) barrier-free per-wave epilogue (drop k1s+barrier);
// (5) hoisted swizzle addressing, unroll 4. TAU=4e-2 top-3 fp64 rescue covers
// key quantization (1.6e-2) + bf16-split error.

typedef float  f32x4  __attribute__((ext_vector_type(4)));
typedef short  bf16x8 __attribute__((ext_vector_type(8)));

#define KK   512
#define DD   64
#define HWSZ 4096
#define NLOC (32*HWSZ)
#define LPB  512
#define TAU  4e-2f
#define KEYMASK 0xFFFFFE00u

static __device__ __forceinline__ unsigned umin(unsigned a, unsigned b) { return a < b ? a : b; }
static __device__ __forceinline__ unsigned umax(unsigned a, unsigned b) { return a > b ? a : b; }

__global__ __launch_bounds__(1024, 4)
void ne_mfma(const float* __restrict__ x, const float* __restrict__ w,
             float* __restrict__ out_res, float* __restrict__ out_idx) {
    __shared__ __align__(16) short wt_hi[KK*DD];   // 64 KB, -2w hi, swizzled
    __shared__ __align__(16) short wt_lo[KK*DD];   // 64 KB, -2w lo, swizzled
    __shared__ __align__(16) float w2s[KK];        // ||w_k||^2 + 128

    const int tid  = threadIdx.x;
    const int lane = tid & 63;
    const int wv   = tid >> 6;       // wave 0..15
    const int col  = lane & 15;      // MFMA col (location within 16-set)
    const int lgr  = lane >> 4;      // lane group 0..3

    const int bloc0 = blockIdx.x * LPB;
    const int bidx  = bloc0 >> 12;
    const long xbase = (long)bidx * (DD*HWSZ);

    char* wh_b = (char*)wt_hi;
    char* wl_b = (char*)wt_lo;

    // ---------- stage -2*W -> LDS bf16 hi/lo (trunc split, swizzled) ----------
    {
        const int n = tid & 511;     // codebook row (k)
        const int h = tid >> 9;      // 0 or 1
        #pragma unroll
        for (int gg = 0; gg < 4; ++gg) {
            const int g = h*4 + gg;
            bf16x8 hv, lv;
            #pragma unroll
            for (int j = 0; j < 8; ++j) {
                float v = -2.0f * w[(g*8 + j)*KK + n];
                unsigned bits = __float_as_uint(v);
                hv[j] = (short)(bits >> 16);                          // trunc hi
                float hi = __uint_as_float(bits & 0xFFFF0000u);
                lv[j] = (short)(__float_as_uint(v - hi) >> 16);       // trunc lo (v-hi exact)
            }
            const int slot = g ^ (n & 7);
            *(bf16x8*)(wh_b + n*128 + slot*16) = hv;
            *(bf16x8*)(wl_b + n*128 + slot*16) = lv;
        }
        if (h == 0) {
            float w2 = 128.0f;       // offset so score+128 > 0 (monotone uint bits)
            #pragma unroll
            for (int d = 0; d < DD; ++d) { float v = w[d*KK + n]; w2 = fmaf(v, v, w2); }
            w2s[n] = w2;
        }
    }

    // ---------- X fragments: 2 sets x 16 locations, bf16 hi/lo (trunc) ----------
    const int wloc0 = bloc0 + wv * 32;
    bf16x8 Xh0[2], Xl0[2], Xh1[2], Xl1[2];
    #pragma unroll
    for (int s = 0; s < 2; ++s) {
        const int hw = (wloc0 + s*16 + col) & 4095;
        #pragma unroll
        for (int c = 0; c < 2; ++c) {
            #pragma unroll
            for (int j = 0; j < 8; ++j) {
                const int d = c*32 + lgr*8 + j;
                float v = x[xbase + (long)d*HWSZ + hw];
                unsigned bits = __float_as_uint(v);
                short hj = (short)(bits >> 16);
                float hi = __uint_as_float(bits & 0xFFFF0000u);
                short lj = (short)(__float_as_uint(v - hi) >> 16);
                if (s == 0) { Xh0[c][j] = hj; Xl0[c][j] = lj; }
                else        { Xh1[c][j] = hj; Xl1[c][j] = lj; }
            }
        }
    }

    __syncthreads();

    // ---------- main loop: MFMA emits score, keyed top-3 tracking ----------
    unsigned u1a = 0xFFFFFFFFu, u2a = 0xFFFFFFFFu, u3a = 0xFFFFFFFFu;
    unsigned u1b = 0xFFFFFFFFu, u2b = 0xFFFFFFFFu, u3b = 0xFFFFFFFFu;

    const int off0 = (col*128 + lgr*16)      ^ ((col & 7) << 4);   // swizzle hoisted
    const int off1 = (col*128 + 64 + lgr*16) ^ ((col & 7) << 4);

    #pragma unroll 4
    for (int t = 0; t < 32; ++t) {
        const f32x4 w2v = *(const f32x4*)((const char*)w2s + t*64 + lgr*16);
        f32x4 acc0 = w2v, acc1 = w2v;      // C init = w2+128 -> acc = score+128
        {
            bf16x8 Wh = *(const bf16x8*)(wh_b + t*2048 + off0);
            bf16x8 Wl = *(const bf16x8*)(wl_b + t*2048 + off0);
            acc0 = __builtin_amdgcn_mfma_f32_16x16x32_bf16(Wl, Xh0[0], acc0, 0,0,0);
            acc0 = __builtin_amdgcn_mfma_f32_16x16x32_bf16(Wh, Xl0[0], acc0, 0,0,0);
            acc0 = __builtin_amdgcn_mfma_f32_16x16x32_bf16(Wh, Xh0[0], acc0, 0,0,0);
            acc1 = __builtin_amdgcn_mfma_f32_16x16x32_bf16(Wl, Xh1[0], acc1, 0,0,0);
            acc1 = __builtin_amdgcn_mfma_f32_16x16x32_bf16(Wh, Xl1[0], acc1, 0,0,0);
            acc1 = __builtin_amdgcn_mfma_f32_16x16x32_bf16(Wh, Xh1[0], acc1, 0,0,0);
        }
        {
            bf16x8 Wh = *(const bf16x8*)(wh_b + t*2048 + off1);
            bf16x8 Wl = *(const bf16x8*)(wl_b + t*2048 + off1);
            acc0 = __builtin_amdgcn_mfma_f32_16x16x32_bf16(Wl, Xh0[1], acc0, 0,0,0);
            acc0 = __builtin_amdgcn_mfma_f32_16x16x32_bf16(Wh, Xl0[1], acc0, 0,0,0);
            acc0 = __builtin_amdgcn_mfma_f32_16x16x32_bf16(Wh, Xh0[1], acc0, 0,0,0);
            acc1 = __builtin_amdgcn_mfma_f32_16x16x32_bf16(Wl, Xh1[1], acc1, 0,0,0);
            acc1 = __builtin_amdgcn_mfma_f32_16x16x32_bf16(Wh, Xl1[1], acc1, 0,0,0);
            acc1 = __builtin_amdgcn_mfma_f32_16x16x32_bf16(Wh, Xh1[1], acc1, 0,0,0);
        }
        const unsigned kb = (unsigned)(t*16 + lgr*4);
        #pragma unroll
        for (int r = 0; r < 4; ++r) {
            {
                unsigned key = (__float_as_uint(acc0[r]) & KEYMASK) | (kb + r);
                unsigned m  = umax(u1a, key);  u1a = umin(u1a, key);
                unsigned m2 = umax(u2a, m);    u2a = umin(u2a, m);
                u3a = umin(u3a, m2);
            }
            {
                unsigned key = (__float_as_uint(acc1[r]) & KEYMASK) | (kb + r);
                unsigned m  = umax(u1b, key);  u1b = umin(u1b, key);
                unsigned m2 = umax(u2b, m);    u2b = umin(u2b, m);
                u3b = umin(u3b, m2);
            }
        }
    }

    // ---------- per-set: shuffle-reduce triples, decode, rescue, write ----------
    const unsigned U1[2] = {u1a, u1b}, U2[2] = {u2a, u2b}, U3[2] = {u3a, u3b};
    #pragma unroll
    for (int s = 0; s < 2; ++s) {
        unsigned a1 = U1[s], a2 = U2[s], a3 = U3[s];
        #pragma unroll
        for (int msk = 16; msk <= 32; msk <<= 1) {
            unsigned b1 = (unsigned)__shfl_xor((int)a1, msk, 64);
            unsigned b2 = (unsigned)__shfl_xor((int)a2, msk, 64);
            unsigned b3 = (unsigned)__shfl_xor((int)a3, msk, 64);
            unsigned c1 = umin(a1,b1), d1v = umax(a1,b1);
            unsigned c2 = umin(a2,b2), d2v = umax(a2,b2);
            unsigned n2 = umin(d1v, c2);
            unsigned e  = umax(d1v, c2);
            unsigned n3 = umin(umin(e, d2v), umin(a3, b3));
            a1 = c1; a2 = n2; a3 = n3;
        }
        int kf = 0;
        if (lane < 16) {
            kf = (int)(a1 & 511u);
            float f1 = __uint_as_float(a1 & KEYMASK);
            float f2 = __uint_as_float(a2 & KEYMASK);
            if (f2 - f1 < TAU) {                    // fp64 rescue (rare)
                float f3 = __uint_as_float(a3 & KEYMASK);
                int cands[3];
                cands[0] = kf;
                cands[1] = (int)(a2 & 511u);
                cands[2] = (f3 - f1 < TAU) ? (int)(a3 & 511u) : -1;
                const int hw = (wloc0 + s*16 + lane) & 4095;
                double bd = 1e300; int bk = 1 << 30;
                #pragma unroll
                for (int ci = 0; ci < 3; ++ci) {
                    int kk = cands[ci];
                    if (kk >= 0) {
                        double dot = 0.0, w2d = 0.0;
                        for (int d = 0; d < DD; ++d) {
                            double wvv = (double)w[(long)d*KK + kk];
                            dot = fma((double)x[xbase + (long)d*HWSZ + hw], wvv, dot);
                            w2d = fma(wvv, wvv, w2d);
                        }
                        double scd = fma(-2.0, dot, w2d);
                        if (scd < bd || (scd == bd && kk < bk)) { bd = scd; bk = kk; }
                    }
                }
                kf = bk;
            }
            out_idx[wloc0 + s*16 + lane] = (float)kf;
        }
        const int kfb = __shfl(kf, col, 64);        // broadcast winner to all lanes
        const int hwb = (wloc0 + s*16) & 4095;
        #pragma unroll
        for (int i = 0; i < 16; ++i) {
            const int d = lgr*16 + i;
            out_res[xbase + (long)d*HWSZ + hwb + col] = w[d*KK + kfb];
        }
    }
}

extern "C" void kernel_launch(void* const* d_in, const int* in_sizes, int n_in,
                              void* d_out, int out_size, void* d_ws, size_t ws_size,
                              hipStream_t stream) {
    const float* x = (const float*)d_in[0];
    const float* w = (const float*)d_in[1];
    float* out = (float*)d_out;
    float* out_res = out;                   // 8388608 floats
    float* out_idx = out + (NLOC * DD);     // 131072 floats (argmin)
    ne_mfma<<<NLOC / LPB, 1024, 0, stream>>>(x, w, out_res, out_idx);
}

// Round 12
// 130.695 us; speedup vs baseline: 1.2825x; 1.2825x over previous
//
#include <hip/hip_runtime.h>

// NearestEmbed via MFMA (Round 9 = bisect of R8 regression).
// R8 (113us vs R7's 60us) changed main loop AND epilogue AND unroll. Evidence:
// WRITE_SIZE 33.3->41.2MB (+25% amplification) implicates the per-wave
// segmented epilogue; divergent per-wave fp64-rescue tail adds unhidden
// latency. This round: KEEP R8 main loop (C-init = w2+128 so MFMA emits the
// score; keyed top-3 min/max tracking), RESTORE R7 epilogue (k1s + barrier +
// dp-split 256B-contiguous stores, measured exact 33280KB) and unroll 2.

typedef float  f32x4  __attribute__((ext_vector_type(4)));
typedef short  bf16x8 __attribute__((ext_vector_type(8)));

#define KK   512
#define DD   64
#define HWSZ 4096
#define NLOC (32*HWSZ)
#define LPB  512
#define TAU  4e-2f
#define KEYMASK 0xFFFFFE00u

static __device__ __forceinline__ unsigned umin(unsigned a, unsigned b) { return a < b ? a : b; }
static __device__ __forceinline__ unsigned umax(unsigned a, unsigned b) { return a > b ? a : b; }

__global__ __launch_bounds__(1024, 4)
void ne_mfma(const float* __restrict__ x, const float* __restrict__ w,
             float* __restrict__ out_res, float* __restrict__ out_idx) {
    __shared__ __align__(16) short wt_hi[KK*DD];   // 64 KB, -2w hi, swizzled
    __shared__ __align__(16) short wt_lo[KK*DD];   // 64 KB, -2w lo, swizzled
    __shared__ __align__(16) float w2s[KK];        // ||w_k||^2 + 128
    __shared__ int k1s[LPB];                       // 2 KB

    const int tid  = threadIdx.x;
    const int lane = tid & 63;
    const int wv   = tid >> 6;       // wave 0..15
    const int col  = lane & 15;      // MFMA col (location within 16-set)
    const int lgr  = lane >> 4;      // lane group 0..3

    const int bloc0 = blockIdx.x * LPB;
    const int bidx  = bloc0 >> 12;
    const long xbase = (long)bidx * (DD*HWSZ);
    const int hw0   = bloc0 & 4095;

    char* wh_b = (char*)wt_hi;
    char* wl_b = (char*)wt_lo;

    // ---------- stage -2*W -> LDS bf16 hi/lo (trunc split, swizzled) ----------
    {
        const int n = tid & 511;     // codebook row (k)
        const int h = tid >> 9;      // 0 or 1
        #pragma unroll
        for (int gg = 0; gg < 4; ++gg) {
            const int g = h*4 + gg;
            bf16x8 hv, lv;
            #pragma unroll
            for (int j = 0; j < 8; ++j) {
                float v = -2.0f * w[(g*8 + j)*KK + n];
                unsigned bits = __float_as_uint(v);
                hv[j] = (short)(bits >> 16);                          // trunc hi
                float hi = __uint_as_float(bits & 0xFFFF0000u);
                lv[j] = (short)(__float_as_uint(v - hi) >> 16);       // trunc lo (v-hi exact)
            }
            const int slot = g ^ (n & 7);
            *(bf16x8*)(wh_b + n*128 + slot*16) = hv;
            *(bf16x8*)(wl_b + n*128 + slot*16) = lv;
        }
        if (h == 0) {
            float w2 = 128.0f;       // offset so score+128 > 0 (monotone uint bits)
            #pragma unroll
            for (int d = 0; d < DD; ++d) { float v = w[d*KK + n]; w2 = fmaf(v, v, w2); }
            w2s[n] = w2;
        }
    }

    // ---------- X fragments: 2 sets x 16 locations, bf16 hi/lo (trunc) ----------
    const int wloc0 = bloc0 + wv * 32;
    bf16x8 Xh0[2], Xl0[2], Xh1[2], Xl1[2];
    #pragma unroll
    for (int s = 0; s < 2; ++s) {
        const int hw = (wloc0 + s*16 + col) & 4095;
        #pragma unroll
        for (int c = 0; c < 2; ++c) {
            #pragma unroll
            for (int j = 0; j < 8; ++j) {
                const int d = c*32 + lgr*8 + j;
                float v = x[xbase + (long)d*HWSZ + hw];
                unsigned bits = __float_as_uint(v);
                short hj = (short)(bits >> 16);
                float hi = __uint_as_float(bits & 0xFFFF0000u);
                short lj = (short)(__float_as_uint(v - hi) >> 16);
                if (s == 0) { Xh0[c][j] = hj; Xl0[c][j] = lj; }
                else        { Xh1[c][j] = hj; Xl1[c][j] = lj; }
            }
        }
    }

    __syncthreads();

    // ---------- main loop: MFMA emits score, keyed top-3 tracking ----------
    unsigned u1a = 0xFFFFFFFFu, u2a = 0xFFFFFFFFu, u3a = 0xFFFFFFFFu;
    unsigned u1b = 0xFFFFFFFFu, u2b = 0xFFFFFFFFu, u3b = 0xFFFFFFFFu;

    const int off0 = (col*128 + lgr*16)      ^ ((col & 7) << 4);   // swizzle hoisted
    const int off1 = (col*128 + 64 + lgr*16) ^ ((col & 7) << 4);

    #pragma unroll 2
    for (int t = 0; t < 32; ++t) {
        const f32x4 w2v = *(const f32x4*)((const char*)w2s + t*64 + lgr*16);
        f32x4 acc0 = w2v, acc1 = w2v;      // C init = w2+128 -> acc = score+128
        {
            bf16x8 Wh = *(const bf16x8*)(wh_b + t*2048 + off0);
            bf16x8 Wl = *(const bf16x8*)(wl_b + t*2048 + off0);
            acc0 = __builtin_amdgcn_mfma_f32_16x16x32_bf16(Wl, Xh0[0], acc0, 0,0,0);
            acc0 = __builtin_amdgcn_mfma_f32_16x16x32_bf16(Wh, Xl0[0], acc0, 0,0,0);
            acc0 = __builtin_amdgcn_mfma_f32_16x16x32_bf16(Wh, Xh0[0], acc0, 0,0,0);
            acc1 = __builtin_amdgcn_mfma_f32_16x16x32_bf16(Wl, Xh1[0], acc1, 0,0,0);
            acc1 = __builtin_amdgcn_mfma_f32_16x16x32_bf16(Wh, Xl1[0], acc1, 0,0,0);
            acc1 = __builtin_amdgcn_mfma_f32_16x16x32_bf16(Wh, Xh1[0], acc1, 0,0,0);
        }
        {
            bf16x8 Wh = *(const bf16x8*)(wh_b + t*2048 + off1);
            bf16x8 Wl = *(const bf16x8*)(wl_b + t*2048 + off1);
            acc0 = __builtin_amdgcn_mfma_f32_16x16x32_bf16(Wl, Xh0[1], acc0, 0,0,0);
            acc0 = __builtin_amdgcn_mfma_f32_16x16x32_bf16(Wh, Xl0[1], acc0, 0,0,0);
            acc0 = __builtin_amdgcn_mfma_f32_16x16x32_bf16(Wh, Xh0[1], acc0, 0,0,0);
            acc1 = __builtin_amdgcn_mfma_f32_16x16x32_bf16(Wl, Xh1[1], acc1, 0,0,0);
            acc1 = __builtin_amdgcn_mfma_f32_16x16x32_bf16(Wh, Xl1[1], acc1, 0,0,0);
            acc1 = __builtin_amdgcn_mfma_f32_16x16x32_bf16(Wh, Xh1[1], acc1, 0,0,0);
        }
        const unsigned kb = (unsigned)(t*16 + lgr*4);
        #pragma unroll
        for (int r = 0; r < 4; ++r) {
            {
                unsigned key = (__float_as_uint(acc0[r]) & KEYMASK) | (kb + r);
                unsigned m  = umax(u1a, key);  u1a = umin(u1a, key);
                unsigned m2 = umax(u2a, m);    u2a = umin(u2a, m);
                u3a = umin(u3a, m2);
            }
            {
                unsigned key = (__float_as_uint(acc1[r]) & KEYMASK) | (kb + r);
                unsigned m  = umax(u1b, key);  u1b = umin(u1b, key);
                unsigned m2 = umax(u2b, m);    u2b = umin(u2b, m);
                u3b = umin(u3b, m2);
            }
        }
    }

    // ---------- per-set: shuffle-reduce triples, decode, rescue ----------
    const unsigned U1[2] = {u1a, u1b}, U2[2] = {u2a, u2b}, U3[2] = {u3a, u3b};
    #pragma unroll
    for (int s = 0; s < 2; ++s) {
        unsigned a1 = U1[s], a2 = U2[s], a3 = U3[s];
        #pragma unroll
        for (int msk = 16; msk <= 32; msk <<= 1) {
            unsigned b1 = (unsigned)__shfl_xor((int)a1, msk, 64);
            unsigned b2 = (unsigned)__shfl_xor((int)a2, msk, 64);
            unsigned b3 = (unsigned)__shfl_xor((int)a3, msk, 64);
            unsigned c1 = umin(a1,b1), d1v = umax(a1,b1);
            unsigned c2 = umin(a2,b2), d2v = umax(a2,b2);
            unsigned n2 = umin(d1v, c2);
            unsigned e  = umax(d1v, c2);
            unsigned n3 = umin(umin(e, d2v), umin(a3, b3));
            a1 = c1; a2 = n2; a3 = n3;
        }
        if (lane < 16) {
            int kf = (int)(a1 & 511u);
            float f1 = __uint_as_float(a1 & KEYMASK);
            float f2 = __uint_as_float(a2 & KEYMASK);
            if (f2 - f1 < TAU) {                    // fp64 rescue (rare)
                float f3 = __uint_as_float(a3 & KEYMASK);
                int cands[3];
                cands[0] = kf;
                cands[1] = (int)(a2 & 511u);
                cands[2] = (f3 - f1 < TAU) ? (int)(a3 & 511u) : -1;
                const int hw = (wloc0 + s*16 + lane) & 4095;
                double bd = 1e300; int bk = 1 << 30;
                #pragma unroll
                for (int ci = 0; ci < 3; ++ci) {
                    int kk = cands[ci];
                    if (kk >= 0) {
                        double dot = 0.0, w2d = 0.0;
                        for (int d = 0; d < DD; ++d) {
                            double wvv = (double)w[(long)d*KK + kk];
                            dot = fma((double)x[xbase + (long)d*HWSZ + hw], wvv, dot);
                            w2d = fma(wvv, wvv, w2d);
                        }
                        double scd = fma(-2.0, dot, w2d);
                        if (scd < bd || (scd == bd && kk < bk)) { bd = scd; bk = kk; }
                    }
                }
                kf = bk;
            }
            const int loc = wloc0 + s*16 + lane;
            k1s[loc - bloc0] = kf;
            out_idx[loc] = (float)kf;
        }
    }

    __syncthreads();

    // ---------- output 0: R7-style coalesced dp-split store ----------
    {
        const int loc = tid & 511;
        const int dp  = tid >> 9;            // 0 or 1
        const int kf  = k1s[loc];
        const long ob = xbase + hw0 + loc;
        #pragma unroll
        for (int i = 0; i < 32; ++i) {
            const int d = i*2 + dp;
            out_res[ob + (long)d*HWSZ] = w[d*KK + kf];
        }
    }
}

extern "C" void kernel_launch(void* const* d_in, const int* in_sizes, int n_in,
                              void* d_out, int out_size, void* d_ws, size_t ws_size,
                              hipStream_t stream) {
    const float* x = (const float*)d_in[0];
    const float* w = (const float*)d_in[1];
    float* out = (float*)d_out;
    float* out_res = out;                   // 8388608 floats
    float* out_idx = out + (NLOC * DD);     // 131072 floats (argmin)
    ne_mfma<<<NLOC / LPB, 1024, 0, stream>>>(x, w, out_res, out_idx);
}